// Round 15
// baseline (83.174 us; speedup 1.0000x reference)
//
#include <hip/hip_runtime.h>
#include <hip/hip_fp16.h>

#define N_POST 50000
#define N_IN   17400
#define NNZ_E  1000000
#define T_DIM  64
#define R_DIM  5
#define NT_DIM 10

#define BROWS  256                                  // rows per bucket
#define NBUCK  ((N_POST + BROWS - 1) / BROWS)       // 196
#define EPB    2048                                 // edges per split block
#define NBLK1  ((NNZ_E + EPB - 1) / EPB)            // 489
#define CAP    64                                   // records per (block,bucket) cell
#define FCAP   5632                                 // max records per bucket (mean 5102)
#define CAPR   7168                                 // padded rec stride per bucket
#define CTILES ((N_IN + 63) / 64)                   // 272

static __device__ __forceinline__ unsigned pack2h(float a, float b) {
    __half2 h = __floats2half2_rn(a, b);
    return *reinterpret_cast<unsigned*>(&h);
}

// ---- fused grid: blocks [0,CTILES) transpose x -> xT fp16 (LDS tile, coalesced
//      both sides); blocks [CTILES, CTILES+NBLK1) single-pass bucket binning ----
__global__ __launch_bounds__(256) void k_ts(const float* __restrict__ x,
                                            __half* __restrict__ xT,
                                            const int2* __restrict__ idx2,
                                            const float* __restrict__ iw,
                                            const int* __restrict__ sid,
                                            unsigned short* __restrict__ cnt,
                                            uint2* __restrict__ rec1) {
    __shared__ float tile[64][65];                  // also covers split's 784B needs
    int bb = blockIdx.x;
    int tid = threadIdx.x;
    if (bb < CTILES) {
        int c0 = bb * 64;
        int l = tid & 63, w = tid >> 6;
        #pragma unroll
        for (int i = 0; i < 16; ++i) {
            int t = i * 4 + w;
            int c = c0 + l;
            tile[l][t] = (c < N_IN) ? x[t * N_IN + c] : 0.f;
        }
        __syncthreads();
        #pragma unroll
        for (int i = 0; i < 16; ++i) {
            int cc = i * 4 + w;
            int c = c0 + cc;
            if (c < N_IN) xT[c * 64 + l] = __float2half(tile[cc][l]);
        }
        return;
    }
    int* lcur = (int*)&tile[0][0];
    for (int i = tid; i < NBUCK; i += 256) lcur[i] = 0;
    __syncthreads();
    int blk = bb - CTILES;
    int base = blk * EPB;
    int n = min(EPB, NNZ_E - base);
    for (int i = tid; i < n; i += 256) {
        int2 rc = idx2[base + i];
        unsigned bk = (unsigned)rc.x >> 8;
        int pos = atomicAdd(&lcur[bk], 1);
        unsigned xx = (unsigned)rc.y | ((unsigned)sid[base + i] << 15)
                    | ((unsigned)(rc.x & 255) << 19);
        rec1[(bk * NBLK1 + blk) * CAP + pos] =
            make_uint2(xx, __float_as_uint(iw[base + i]));
    }
    __syncthreads();
    for (int i = tid; i < NBUCK; i += 256)
        cnt[i * NBLK1 + blk] = (unsigned short)lcur[i];
}

// ---- per-bucket: parallel slot-compact cells into LDS, row-hist, scan,
//      emit padded fp16 records { col<<7, h2(wf0,wf1), h2(wf2,wf3), h2(wf4,0) } ----
__global__ __launch_bounds__(512) void k_fine(const uint2* __restrict__ rec1,
                                              const unsigned short* __restrict__ cnt,
                                              const float* __restrict__ S,
                                              uint4* __restrict__ rec,
                                              int* __restrict__ rstart,
                                              int* __restrict__ plen) {
    __shared__ uint2 lrec[FCAP];
    __shared__ int scnt[512];
    __shared__ int soff[512];
    __shared__ int lhist[BROWS];
    __shared__ int lsc[BROWS];
    __shared__ int lcur[BROWS];
    __shared__ float s_S[NT_DIM * R_DIM];
    int t = threadIdx.x;
    int b = blockIdx.x;
    int pbase = b * CAPR;
    if (t < NT_DIM * R_DIM) s_S[t] = S[t];
    int cv = (t < NBLK1) ? (int)cnt[b * NBLK1 + t] : 0;
    scnt[t] = cv;
    soff[t] = cv;
    if (t < 256) lhist[t] = 0;
    __syncthreads();
    // scan 512 cell counts -> cell offsets
    for (int off = 1; off < 512; off <<= 1) {
        int u = (t >= off) ? soff[t - off] : 0;
        __syncthreads();
        soff[t] += u;
        __syncthreads();
    }
    soff[t] -= cv;                                  // exclusive
    __syncthreads();
    // parallel slot-based compaction: all 512 threads, predicated loads
    const uint2* srcb = rec1 + (size_t)b * NBLK1 * CAP;
    for (int slot = t; slot < NBLK1 * CAP; slot += 512) {
        int cell = slot >> 6;
        int j = slot & 63;
        if (j < scnt[cell]) lrec[soff[cell] + j] = srcb[slot];
    }
    int nrec = soff[511] + scnt[511];
    __syncthreads();
    // row histogram
    for (int i = t; i < nrec; i += 512)
        atomicAdd(&lhist[(lrec[i].x >> 19) & 255], 1);
    __syncthreads();
    int v = 0, vp = 0;
    if (t < 256) { v = lhist[t]; vp = (v + 3) & ~3; lsc[t] = vp; }
    __syncthreads();
    for (int off = 1; off < 256; off <<= 1) {
        int u = 0;
        if (t < 256 && t >= off) u = lsc[t - off];
        __syncthreads();
        if (t < 256) lsc[t] += u;
        __syncthreads();
    }
    if (t < 256) {
        int exclp = lsc[t] - vp;
        int p = b * BROWS + t;
        if (p < N_POST) { rstart[p] = pbase + exclp; plen[p] = vp; }
        lcur[t] = exclp;
    }
    __syncthreads();
    // scatter to final padded row-sorted order, scaling weights by S
    for (int i = t; i < nrec; i += 512) {
        uint2 rc = lrec[i];
        int r = (rc.x >> 19) & 255;
        int pos = atomicAdd(&lcur[r], 1);
        unsigned col = rc.x & 0x7FFF;
        const float* f = &s_S[((rc.x >> 15) & 0xF) * R_DIM];
        float w = __uint_as_float(rc.y);
        uint4 r4;
        r4.x = col << 7;                 // byte offset into fp16 xT
        r4.y = pack2h(w * f[0], w * f[1]);
        r4.z = pack2h(w * f[2], w * f[3]);
        r4.w = pack2h(w * f[4], 0.f);
        rec[pbase + pos] = r4;
    }
    // zero-pad each row to its multiple of 4
    if (t < 256) {
        int exclp = lsc[t] - vp;
        for (int u = v; u < vp; ++u)
            rec[pbase + exclp + u] = make_uint4(0, 0, 0, 0);
    }
}

// FMA of one record into the 10 accumulators (2 t-values x 5 r) via v_fma_mix_f32
#define FMAREC(Rk, Xk)                                                              \
    do {                                                                            \
        unsigned x_ = (Xk);                                                         \
        unsigned w01_ = (Rk).y, w23_ = (Rk).z, w4_ = (Rk).w;                        \
        asm("v_fma_mix_f32 %0, %1, %2, %0 op_sel:[0,0,0] op_sel_hi:[1,1,0]"         \
            : "+v"(a0e) : "v"(x_), "v"(w01_));                                      \
        asm("v_fma_mix_f32 %0, %1, %2, %0 op_sel:[1,0,0] op_sel_hi:[1,1,0]"         \
            : "+v"(a0o) : "v"(x_), "v"(w01_));                                      \
        asm("v_fma_mix_f32 %0, %1, %2, %0 op_sel:[0,1,0] op_sel_hi:[1,1,0]"         \
            : "+v"(a1e) : "v"(x_), "v"(w01_));                                      \
        asm("v_fma_mix_f32 %0, %1, %2, %0 op_sel:[1,1,0] op_sel_hi:[1,1,0]"         \
            : "+v"(a1o) : "v"(x_), "v"(w01_));                                      \
        asm("v_fma_mix_f32 %0, %1, %2, %0 op_sel:[0,0,0] op_sel_hi:[1,1,0]"         \
            : "+v"(a2e) : "v"(x_), "v"(w23_));                                      \
        asm("v_fma_mix_f32 %0, %1, %2, %0 op_sel:[1,0,0] op_sel_hi:[1,1,0]"         \
            : "+v"(a2o) : "v"(x_), "v"(w23_));                                      \
        asm("v_fma_mix_f32 %0, %1, %2, %0 op_sel:[0,1,0] op_sel_hi:[1,1,0]"         \
            : "+v"(a3e) : "v"(x_), "v"(w23_));                                      \
        asm("v_fma_mix_f32 %0, %1, %2, %0 op_sel:[1,1,0] op_sel_hi:[1,1,0]"         \
            : "+v"(a3o) : "v"(x_), "v"(w23_));                                      \
        asm("v_fma_mix_f32 %0, %1, %2, %0 op_sel:[0,0,0] op_sel_hi:[1,1,0]"         \
            : "+v"(a4e) : "v"(x_), "v"(w4_));                                       \
        asm("v_fma_mix_f32 %0, %1, %2, %0 op_sel:[1,0,0] op_sel_hi:[1,1,0]"         \
            : "+v"(a4o) : "v"(x_), "v"(w4_));                                       \
    } while (0)

// ---- phase2: 16 rows/block; half-wave per row; half2 gather; depth-2 pipeline;
//      7 waves/SIMD (LDS allows 7 blocks/CU; VGPR budget 73 >> 36 used) ----
__global__ __launch_bounds__(256, 7) void k_phase2(
        const __half* __restrict__ xT, const int* __restrict__ rstart,
        const int* __restrict__ plen, const uint4* __restrict__ rec,
        float* __restrict__ out) {
    __shared__ float o_lds[T_DIM * 81];
    const char* xb = (const char*)xT;
    int tid = threadIdx.x;
    int wave = tid >> 6, lane = tid & 63;
    int half = lane >> 5;
    int lane4 = (lane & 31) * 4;          // byte offset of my half2 within a col row
    #pragma unroll
    for (int h = 0; h < 2; ++h) {
        int pa = blockIdx.x * 16 + wave * 4 + h * 2;
        int myrow = pa + half;
        int ih = rstart[myrow];
        int ng = plen[myrow] >> 2;        // my row's group count
        int na = plen[pa], nb = plen[pa + 1];
        int ngmax = __builtin_amdgcn_readfirstlane((na > nb ? na : nb) >> 2);
        const uint4* rp = rec + ih;
        float a0e = 0.f, a0o = 0.f, a1e = 0.f, a1o = 0.f, a2e = 0.f;
        float a2o = 0.f, a3e = 0.f, a3o = 0.f, a4e = 0.f, a4o = 0.f;
        uint4 R0, R1, R2, R3;
        unsigned X0, X1, X2, X3;
        if (0 < ng) {
            R0 = rp[0]; R1 = rp[1]; R2 = rp[2]; R3 = rp[3];
            X0 = *(const unsigned*)(xb + (R0.x + lane4));
            X1 = *(const unsigned*)(xb + (R1.x + lane4));
            X2 = *(const unsigned*)(xb + (R2.x + lane4));
            X3 = *(const unsigned*)(xb + (R3.x + lane4));
        } else {
            R0 = R1 = R2 = R3 = make_uint4(0, 0, 0, 0);
            X0 = X1 = X2 = X3 = 0;
        }
        for (int g = 1; g < ngmax; ++g) {
            uint4 S0, S1, S2, S3;
            unsigned Y0, Y1, Y2, Y3;
            if (g < ng) {
                const uint4* q = rp + (g << 2);
                S0 = q[0]; S1 = q[1]; S2 = q[2]; S3 = q[3];
                Y0 = *(const unsigned*)(xb + (S0.x + lane4));
                Y1 = *(const unsigned*)(xb + (S1.x + lane4));
                Y2 = *(const unsigned*)(xb + (S2.x + lane4));
                Y3 = *(const unsigned*)(xb + (S3.x + lane4));
            } else {
                S0 = S1 = S2 = S3 = make_uint4(0, 0, 0, 0);
                Y0 = Y1 = Y2 = Y3 = 0;
            }
            FMAREC(R0, X0); FMAREC(R1, X1); FMAREC(R2, X2); FMAREC(R3, X3);
            R0 = S0; R1 = S1; R2 = S2; R3 = S3;
            X0 = Y0; X1 = Y1; X2 = Y2; X3 = Y3;
        }
        if (ngmax > 0) {
            FMAREC(R0, X0); FMAREC(R1, X1); FMAREC(R2, X2); FMAREC(R3, X3);
        }
        int rowl = wave * 4 + h * 2 + half;
        int t0 = (lane & 31) * 2;
        float* d0 = &o_lds[t0 * 81 + rowl * 5];
        d0[0] = a0e; d0[1] = a1e; d0[2] = a2e; d0[3] = a3e; d0[4] = a4e;
        float* d1 = &o_lds[(t0 + 1) * 81 + rowl * 5];
        d1[0] = a0o; d1[1] = a1o; d1[2] = a2o; d1[3] = a3o; d1[4] = a4o;
    }
    __syncthreads();
    int base5 = blockIdx.x * 80;
    for (int i2 = tid; i2 < T_DIM * 80; i2 += 256) {
        int t = i2 / 80;
        int j = i2 - t * 80;
        out[(size_t)t * (N_POST * R_DIM) + base5 + j] = o_lds[t * 81 + j];
    }
}

extern "C" void kernel_launch(void* const* d_in, const int* in_sizes, int n_in,
                              void* d_out, int out_size, void* d_ws, size_t ws_size,
                              hipStream_t stream) {
    const float* inp  = (const float*)d_in[0];
    const int2*  idx2 = (const int2*)d_in[1];
    const float* iw   = (const float*)d_in[2];
    const float* S    = (const float*)d_in[3];
    const int*   sid  = (const int*)d_in[4];
    float* out = (float*)d_out;

    char* ws = (char*)d_ws;
    size_t off = 0;
    auto alloc = [&](size_t bytes) -> void* {
        void* p = ws + off;
        off += (bytes + 255) & ~(size_t)255;
        return p;
    };
    __half* xT            = (__half*)alloc((size_t)N_IN * T_DIM * 2);
    unsigned short* cnt   = (unsigned short*)alloc((size_t)NBUCK * NBLK1 * 2);
    int*   rstart         = (int*)alloc((size_t)N_POST * 4);
    int*   plen           = (int*)alloc((size_t)N_POST * 4);
    uint2* rec1           = (uint2*)alloc((size_t)NBUCK * NBLK1 * CAP * 8);
    uint4* rec            = (uint4*)alloc((size_t)NBUCK * CAPR * 16);

    k_ts<<<CTILES + NBLK1, 256, 0, stream>>>(inp, xT, idx2, iw, sid, cnt, rec1);
    k_fine<<<NBUCK, 512, 0, stream>>>(rec1, cnt, S, rec, rstart, plen);
    k_phase2<<<N_POST / 16, 256, 0, stream>>>(xT, rstart, plen, rec, out);
}

// Round 16
// 74.682 us; speedup vs baseline: 1.1137x; 1.1137x over previous
//
#include <hip/hip_runtime.h>
#include <hip/hip_fp16.h>

#define N_POST 50000
#define N_IN   17400
#define NNZ_E  1000000
#define T_DIM  64
#define R_DIM  5
#define NT_DIM 10

#define BROWS  256                                  // rows per bucket
#define NBUCK  ((N_POST + BROWS - 1) / BROWS)       // 196
#define EPB    4096                                 // edges per split block
#define NBLK1  ((NNZ_E + EPB - 1) / EPB)            // 245
#define CAP    64                                   // records per (block,bucket) cell
#define FCAP   5632                                 // max records per bucket (mean 5102)
#define CAPR   7168                                 // padded rec stride per bucket
#define CTILES ((N_IN + 63) / 64)                   // 272
#define RECBUF_N 1024                               // staged records per phase2 block

static __device__ __forceinline__ unsigned pack2h(float a, float b) {
    __half2 h = __floats2half2_rn(a, b);
    return *reinterpret_cast<unsigned*>(&h);
}

// ---- fused grid: blocks [0,CTILES) transpose x -> xT fp16 (LDS tile, coalesced
//      both sides); blocks [CTILES, CTILES+NBLK1) single-pass bucket binning ----
__global__ __launch_bounds__(256) void k_ts(const float* __restrict__ x,
                                            __half* __restrict__ xT,
                                            const int2* __restrict__ idx2,
                                            const float* __restrict__ iw,
                                            const int* __restrict__ sid,
                                            unsigned short* __restrict__ cnt,
                                            uint2* __restrict__ rec1) {
    __shared__ float tile[64][65];
    int bb = blockIdx.x;
    int tid = threadIdx.x;
    if (bb < CTILES) {
        int c0 = bb * 64;
        int l = tid & 63, w = tid >> 6;
        #pragma unroll
        for (int i = 0; i < 16; ++i) {
            int t = i * 4 + w;
            int c = c0 + l;
            tile[l][t] = (c < N_IN) ? x[t * N_IN + c] : 0.f;
        }
        __syncthreads();
        #pragma unroll
        for (int i = 0; i < 16; ++i) {
            int cc = i * 4 + w;
            int c = c0 + cc;
            if (c < N_IN) xT[c * 64 + l] = __float2half(tile[cc][l]);
        }
        return;
    }
    int* lcur = (int*)&tile[0][0];
    for (int i = tid; i < NBUCK; i += 256) lcur[i] = 0;
    __syncthreads();
    int blk = bb - CTILES;
    int base = blk * EPB;
    int n = min(EPB, NNZ_E - base);
    for (int i = tid; i < n; i += 256) {
        int2 rc = idx2[base + i];
        unsigned bk = (unsigned)rc.x >> 8;
        int pos = atomicAdd(&lcur[bk], 1);
        unsigned xx = (unsigned)rc.y | ((unsigned)sid[base + i] << 15)
                    | ((unsigned)(rc.x & 255) << 19);
        rec1[(bk * NBLK1 + blk) * CAP + pos] =
            make_uint2(xx, __float_as_uint(iw[base + i]));
    }
    __syncthreads();
    for (int i = tid; i < NBUCK; i += 256)
        cnt[i * NBLK1 + blk] = (unsigned short)lcur[i];
}

// ---- per-bucket: parallel slot-compact cells into LDS, row-hist, scan,
//      emit padded fp16 records { col<<7, h2(wf0,wf1), h2(wf2,wf3), h2(wf4,0) } ----
__global__ __launch_bounds__(512) void k_fine(const uint2* __restrict__ rec1,
                                              const unsigned short* __restrict__ cnt,
                                              const float* __restrict__ S,
                                              uint4* __restrict__ rec,
                                              int* __restrict__ rstart,
                                              int* __restrict__ plen) {
    __shared__ uint2 lrec[FCAP];
    __shared__ int scnt[256];
    __shared__ int soff[256];
    __shared__ int lhist[BROWS];
    __shared__ int lsc[BROWS];
    __shared__ int lcur[BROWS];
    __shared__ float s_S[NT_DIM * R_DIM];
    int t = threadIdx.x;
    int b = blockIdx.x;
    int pbase = b * CAPR;
    if (t < NT_DIM * R_DIM) s_S[t] = S[t];
    int cv = 0;
    if (t < 256) {
        cv = (t < NBLK1) ? (int)cnt[b * NBLK1 + t] : 0;
        scnt[t] = cv;
        soff[t] = cv;
        lhist[t] = 0;
    }
    __syncthreads();
    for (int off = 1; off < 256; off <<= 1) {
        int u = 0;
        if (t < 256 && t >= off) u = soff[t - off];
        __syncthreads();
        if (t < 256) soff[t] += u;
        __syncthreads();
    }
    if (t < 256) soff[t] -= cv;                    // exclusive
    __syncthreads();
    const uint2* srcb = rec1 + (size_t)b * NBLK1 * CAP;
    for (int slot = t; slot < NBLK1 * CAP; slot += 512) {
        int cell = slot >> 6;
        int j = slot & 63;
        if (j < scnt[cell]) lrec[soff[cell] + j] = srcb[slot];
    }
    int nrec = soff[255] + scnt[255];
    __syncthreads();
    for (int i = t; i < nrec; i += 512)
        atomicAdd(&lhist[(lrec[i].x >> 19) & 255], 1);
    __syncthreads();
    int v = 0, vp = 0;
    if (t < 256) { v = lhist[t]; vp = (v + 3) & ~3; lsc[t] = vp; }
    __syncthreads();
    for (int off = 1; off < 256; off <<= 1) {
        int u = 0;
        if (t < 256 && t >= off) u = lsc[t - off];
        __syncthreads();
        if (t < 256) lsc[t] += u;
        __syncthreads();
    }
    if (t < 256) {
        int exclp = lsc[t] - vp;
        int p = b * BROWS + t;
        if (p < N_POST) { rstart[p] = pbase + exclp; plen[p] = vp; }
        lcur[t] = exclp;
    }
    __syncthreads();
    for (int i = t; i < nrec; i += 512) {
        uint2 rc = lrec[i];
        int r = (rc.x >> 19) & 255;
        int pos = atomicAdd(&lcur[r], 1);
        unsigned col = rc.x & 0x7FFF;
        const float* f = &s_S[((rc.x >> 15) & 0xF) * R_DIM];
        float w = __uint_as_float(rc.y);
        uint4 r4;
        r4.x = col << 7;                 // byte offset into fp16 xT
        r4.y = pack2h(w * f[0], w * f[1]);
        r4.z = pack2h(w * f[2], w * f[3]);
        r4.w = pack2h(w * f[4], 0.f);
        rec[pbase + pos] = r4;
    }
    if (t < 256) {
        int exclp = lsc[t] - vp;
        for (int u = v; u < vp; ++u)
            rec[pbase + exclp + u] = make_uint4(0, 0, 0, 0);
    }
}

// FMA of one record into the 10 accumulators (2 t-values x 5 r) via v_fma_mix_f32
#define FMAREC(Rk, Xk)                                                              \
    do {                                                                            \
        unsigned x_ = (Xk);                                                         \
        unsigned w01_ = (Rk).y, w23_ = (Rk).z, w4_ = (Rk).w;                        \
        asm("v_fma_mix_f32 %0, %1, %2, %0 op_sel:[0,0,0] op_sel_hi:[1,1,0]"         \
            : "+v"(a0e) : "v"(x_), "v"(w01_));                                      \
        asm("v_fma_mix_f32 %0, %1, %2, %0 op_sel:[1,0,0] op_sel_hi:[1,1,0]"         \
            : "+v"(a0o) : "v"(x_), "v"(w01_));                                      \
        asm("v_fma_mix_f32 %0, %1, %2, %0 op_sel:[0,1,0] op_sel_hi:[1,1,0]"         \
            : "+v"(a1e) : "v"(x_), "v"(w01_));                                      \
        asm("v_fma_mix_f32 %0, %1, %2, %0 op_sel:[1,1,0] op_sel_hi:[1,1,0]"         \
            : "+v"(a1o) : "v"(x_), "v"(w01_));                                      \
        asm("v_fma_mix_f32 %0, %1, %2, %0 op_sel:[0,0,0] op_sel_hi:[1,1,0]"         \
            : "+v"(a2e) : "v"(x_), "v"(w23_));                                      \
        asm("v_fma_mix_f32 %0, %1, %2, %0 op_sel:[1,0,0] op_sel_hi:[1,1,0]"         \
            : "+v"(a2o) : "v"(x_), "v"(w23_));                                      \
        asm("v_fma_mix_f32 %0, %1, %2, %0 op_sel:[0,1,0] op_sel_hi:[1,1,0]"         \
            : "+v"(a3e) : "v"(x_), "v"(w23_));                                      \
        asm("v_fma_mix_f32 %0, %1, %2, %0 op_sel:[1,1,0] op_sel_hi:[1,1,0]"         \
            : "+v"(a3o) : "v"(x_), "v"(w23_));                                      \
        asm("v_fma_mix_f32 %0, %1, %2, %0 op_sel:[0,0,0] op_sel_hi:[1,1,0]"         \
            : "+v"(a4e) : "v"(x_), "v"(w4_));                                       \
        asm("v_fma_mix_f32 %0, %1, %2, %0 op_sel:[1,0,0] op_sel_hi:[1,1,0]"         \
            : "+v"(a4o) : "v"(x_), "v"(w4_));                                       \
    } while (0)

// per-h accumulation body, parameterized on the record pointer (LDS or global)
#define ROWBODY(RP)                                                                 \
    do {                                                                            \
        if (0 < ng) {                                                               \
            R0 = (RP)[0]; R1 = (RP)[1]; R2 = (RP)[2]; R3 = (RP)[3];                 \
            X0 = *(const unsigned*)(xb + (R0.x + lane4));                           \
            X1 = *(const unsigned*)(xb + (R1.x + lane4));                           \
            X2 = *(const unsigned*)(xb + (R2.x + lane4));                           \
            X3 = *(const unsigned*)(xb + (R3.x + lane4));                           \
        } else {                                                                    \
            R0 = R1 = R2 = R3 = make_uint4(0, 0, 0, 0);                             \
            X0 = X1 = X2 = X3 = 0;                                                  \
        }                                                                           \
        for (int g = 1; g < ngmax; ++g) {                                           \
            uint4 S0, S1, S2, S3;                                                   \
            unsigned Y0, Y1, Y2, Y3;                                                \
            if (g < ng) {                                                           \
                S0 = (RP)[(g << 2)];     S1 = (RP)[(g << 2) + 1];                   \
                S2 = (RP)[(g << 2) + 2]; S3 = (RP)[(g << 2) + 3];                   \
                Y0 = *(const unsigned*)(xb + (S0.x + lane4));                       \
                Y1 = *(const unsigned*)(xb + (S1.x + lane4));                       \
                Y2 = *(const unsigned*)(xb + (S2.x + lane4));                       \
                Y3 = *(const unsigned*)(xb + (S3.x + lane4));                       \
            } else {                                                                \
                S0 = S1 = S2 = S3 = make_uint4(0, 0, 0, 0);                         \
                Y0 = Y1 = Y2 = Y3 = 0;                                              \
            }                                                                       \
            FMAREC(R0, X0); FMAREC(R1, X1); FMAREC(R2, X2); FMAREC(R3, X3);         \
            R0 = S0; R1 = S1; R2 = S2; R3 = S3;                                     \
            X0 = Y0; X1 = Y1; X2 = Y2; X3 = Y3;                                     \
        }                                                                           \
        if (ngmax > 0) {                                                            \
            FMAREC(R0, X0); FMAREC(R1, X1); FMAREC(R2, X2); FMAREC(R3, X3);         \
        }                                                                           \
    } while (0)

// ---- phase2: 16 rows/block; block's record range LDS-staged (contiguous in rec);
//      half-wave per row; half2 gather is the ONLY VMEM op in the hot loop ----
__global__ __launch_bounds__(256, 4) void k_phase2(
        const __half* __restrict__ xT, const int* __restrict__ rstart,
        const int* __restrict__ plen, const uint4* __restrict__ rec,
        float* __restrict__ out) {
    __shared__ float o_lds[T_DIM * 81];
    __shared__ uint4 recbuf[RECBUF_N];
    const char* xb = (const char*)xT;
    int tid = threadIdx.x;
    int wave = tid >> 6, lane = tid & 63;
    int half = lane >> 5;
    int lane4 = (lane & 31) * 4;
    int p0 = blockIdx.x * 16;
    int start0 = rstart[p0];
    int nblk = rstart[p0 + 15] + plen[p0 + 15] - start0;   // rows contiguous in rec
    bool uselds = (nblk <= RECBUF_N);                      // block-uniform
    if (uselds) {
        for (int i = tid; i < nblk; i += 256) recbuf[i] = rec[start0 + i];
    }
    __syncthreads();
    #pragma unroll
    for (int h = 0; h < 2; ++h) {
        int pa = p0 + wave * 4 + h * 2;
        int myrow = pa + half;
        int ih = rstart[myrow];
        int ng = plen[myrow] >> 2;
        int na = plen[pa], nb = plen[pa + 1];
        int ngmax = __builtin_amdgcn_readfirstlane((na > nb ? na : nb) >> 2);
        float a0e = 0.f, a0o = 0.f, a1e = 0.f, a1o = 0.f, a2e = 0.f;
        float a2o = 0.f, a3e = 0.f, a3o = 0.f, a4e = 0.f, a4o = 0.f;
        uint4 R0, R1, R2, R3;
        unsigned X0, X1, X2, X3;
        if (uselds) {
            const uint4* rp = recbuf + (ih - start0);      // ds_read path
            ROWBODY(rp);
        } else {
            const uint4* rp = rec + ih;                    // cold fallback
            ROWBODY(rp);
        }
        int rowl = wave * 4 + h * 2 + half;
        int t0 = (lane & 31) * 2;
        float* d0 = &o_lds[t0 * 81 + rowl * 5];
        d0[0] = a0e; d0[1] = a1e; d0[2] = a2e; d0[3] = a3e; d0[4] = a4e;
        float* d1 = &o_lds[(t0 + 1) * 81 + rowl * 5];
        d1[0] = a0o; d1[1] = a1o; d1[2] = a2o; d1[3] = a3o; d1[4] = a4o;
    }
    __syncthreads();
    int base5 = blockIdx.x * 80;
    for (int i2 = tid; i2 < T_DIM * 80; i2 += 256) {
        int t = i2 / 80;
        int j = i2 - t * 80;
        out[(size_t)t * (N_POST * R_DIM) + base5 + j] = o_lds[t * 81 + j];
    }
}

extern "C" void kernel_launch(void* const* d_in, const int* in_sizes, int n_in,
                              void* d_out, int out_size, void* d_ws, size_t ws_size,
                              hipStream_t stream) {
    const float* inp  = (const float*)d_in[0];
    const int2*  idx2 = (const int2*)d_in[1];
    const float* iw   = (const float*)d_in[2];
    const float* S    = (const float*)d_in[3];
    const int*   sid  = (const int*)d_in[4];
    float* out = (float*)d_out;

    char* ws = (char*)d_ws;
    size_t off = 0;
    auto alloc = [&](size_t bytes) -> void* {
        void* p = ws + off;
        off += (bytes + 255) & ~(size_t)255;
        return p;
    };
    __half* xT            = (__half*)alloc((size_t)N_IN * T_DIM * 2);
    unsigned short* cnt   = (unsigned short*)alloc((size_t)NBUCK * NBLK1 * 2);
    int*   rstart         = (int*)alloc((size_t)N_POST * 4);
    int*   plen           = (int*)alloc((size_t)N_POST * 4);
    uint2* rec1           = (uint2*)alloc((size_t)NBUCK * NBLK1 * CAP * 8);
    uint4* rec            = (uint4*)alloc((size_t)NBUCK * CAPR * 16);

    k_ts<<<CTILES + NBLK1, 256, 0, stream>>>(inp, xT, idx2, iw, sid, cnt, rec1);
    k_fine<<<NBUCK, 512, 0, stream>>>(rec1, cnt, S, rec, rstart, plen);
    k_phase2<<<N_POST / 16, 256, 0, stream>>>(xT, rstart, plen, rec, out);
}

// Round 17
// 67.794 us; speedup vs baseline: 1.2269x; 1.1016x over previous
//
#include <hip/hip_runtime.h>
#include <hip/hip_fp16.h>

#define N_POST 50000
#define N_IN   17400
#define NNZ_E  1000000
#define T_DIM  64
#define R_DIM  5
#define NT_DIM 10

#define BROWS  256                                  // rows per bucket
#define NBUCK  ((N_POST + BROWS - 1) / BROWS)       // 196
#define EPB    4096                                 // edges per split block
#define NBLK1  ((NNZ_E + EPB - 1) / EPB)            // 245
#define CAP    64                                   // records per (block,bucket) cell
#define FCAP   5632                                 // max records per bucket (mean 5102)
#define CAPR   7168                                 // padded rec stride per bucket
#define CTILES ((N_IN + 63) / 64)                   // 272
#define RECBUF_N 1024                               // staged records per phase2 block

static __device__ __forceinline__ unsigned pack2h(float a, float b) {
    __half2 h = __floats2half2_rn(a, b);
    return *reinterpret_cast<unsigned*>(&h);
}

// ---- fused grid (1024 threads): blocks [0,CTILES) transpose one 64-col tile;
//      blocks [CTILES, CTILES+NBLK1) single-pass bucket binning (4 waves/SIMD) ----
__global__ __launch_bounds__(1024) void k_ts(const float* __restrict__ x,
                                             __half* __restrict__ xT,
                                             const int2* __restrict__ idx2,
                                             const float* __restrict__ iw,
                                             const int* __restrict__ sid,
                                             unsigned short* __restrict__ cnt,
                                             uint2* __restrict__ rec1) {
    __shared__ float tile[64][65];
    int bb = blockIdx.x;
    int tid = threadIdx.x;
    if (bb < CTILES) {
        int c0 = bb * 64;
        int l = tid & 63, w = tid >> 6;             // w: 0..15
        #pragma unroll
        for (int i = 0; i < 4; ++i) {
            int t = i * 16 + w;
            int c = c0 + l;
            tile[l][t] = (c < N_IN) ? x[t * N_IN + c] : 0.f;
        }
        __syncthreads();
        #pragma unroll
        for (int i = 0; i < 4; ++i) {
            int cc = i * 16 + w;
            int c = c0 + cc;
            if (c < N_IN) xT[c * 64 + l] = __float2half(tile[cc][l]);
        }
        return;
    }
    int* lcur = (int*)&tile[0][0];
    for (int i = tid; i < NBUCK; i += 1024) lcur[i] = 0;
    __syncthreads();
    int blk = bb - CTILES;
    int base = blk * EPB;
    int n = min(EPB, NNZ_E - base);
    for (int i = tid; i < n; i += 1024) {
        int2 rc = idx2[base + i];
        unsigned bk = (unsigned)rc.x >> 8;
        int pos = atomicAdd(&lcur[bk], 1);
        unsigned xx = (unsigned)rc.y | ((unsigned)sid[base + i] << 15)
                    | ((unsigned)(rc.x & 255) << 19);
        rec1[(bk * NBLK1 + blk) * CAP + pos] =
            make_uint2(xx, __float_as_uint(iw[base + i]));
    }
    __syncthreads();
    for (int i = tid; i < NBUCK; i += 1024)
        cnt[i * NBLK1 + blk] = (unsigned short)lcur[i];
}

// ---- per-bucket: parallel slot-compact cells into LDS, row-hist, scan,
//      emit fp16 records padded so PAIRED rows (2k,2k+1) have EQUAL length ----
__global__ __launch_bounds__(512) void k_fine(const uint2* __restrict__ rec1,
                                              const unsigned short* __restrict__ cnt,
                                              const float* __restrict__ S,
                                              uint4* __restrict__ rec,
                                              int* __restrict__ rstart,
                                              int* __restrict__ plen) {
    __shared__ uint2 lrec[FCAP];
    __shared__ int scnt[256];
    __shared__ int soff[256];
    __shared__ int lhist[BROWS];
    __shared__ int lsc[BROWS];
    __shared__ int lcur[BROWS];
    __shared__ float s_S[NT_DIM * R_DIM];
    int t = threadIdx.x;
    int b = blockIdx.x;
    int pbase = b * CAPR;
    if (t < NT_DIM * R_DIM) s_S[t] = S[t];
    int cv = 0;
    if (t < 256) {
        cv = (t < NBLK1) ? (int)cnt[b * NBLK1 + t] : 0;
        scnt[t] = cv;
        soff[t] = cv;
        lhist[t] = 0;
    }
    __syncthreads();
    for (int off = 1; off < 256; off <<= 1) {
        int u = 0;
        if (t < 256 && t >= off) u = soff[t - off];
        __syncthreads();
        if (t < 256) soff[t] += u;
        __syncthreads();
    }
    if (t < 256) soff[t] -= cv;                    // exclusive
    __syncthreads();
    const uint2* srcb = rec1 + (size_t)b * NBLK1 * CAP;
    for (int slot = t; slot < NBLK1 * CAP; slot += 512) {
        int cell = slot >> 6;
        int j = slot & 63;
        if (j < scnt[cell]) lrec[soff[cell] + j] = srcb[slot];
    }
    int nrec = soff[255] + scnt[255];
    __syncthreads();
    for (int i = t; i < nrec; i += 512)
        atomicAdd(&lhist[(lrec[i].x >> 19) & 255], 1);
    __syncthreads();
    // pair-equal padded lengths: vp = max over the row pair of (v rounded to 4)
    if (t < 256) soff[t] = (lhist[t] + 3) & ~3;    // reuse soff as vp4 scratch
    __syncthreads();
    int v = 0, vp = 0;
    if (t < 256) {
        v = lhist[t];
        vp = max(soff[t], soff[t ^ 1]);            // pair max (rows 2k,2k+1)
        lsc[t] = vp;
    }
    __syncthreads();
    for (int off = 1; off < 256; off <<= 1) {
        int u = 0;
        if (t < 256 && t >= off) u = lsc[t - off];
        __syncthreads();
        if (t < 256) lsc[t] += u;
        __syncthreads();
    }
    if (t < 256) {
        int exclp = lsc[t] - vp;
        int p = b * BROWS + t;
        if (p < N_POST) { rstart[p] = pbase + exclp; plen[p] = vp; }
        lcur[t] = exclp;
    }
    __syncthreads();
    for (int i = t; i < nrec; i += 512) {
        uint2 rc = lrec[i];
        int r = (rc.x >> 19) & 255;
        int pos = atomicAdd(&lcur[r], 1);
        unsigned col = rc.x & 0x7FFF;
        const float* f = &s_S[((rc.x >> 15) & 0xF) * R_DIM];
        float w = __uint_as_float(rc.y);
        uint4 r4;
        r4.x = col << 7;                 // byte offset into fp16 xT
        r4.y = pack2h(w * f[0], w * f[1]);
        r4.z = pack2h(w * f[2], w * f[3]);
        r4.w = pack2h(w * f[4], 0.f);
        rec[pbase + pos] = r4;
    }
    if (t < 256) {
        int exclp = lsc[t] - vp;
        for (int u = v; u < vp; ++u)
            rec[pbase + exclp + u] = make_uint4(0, 0, 0, 0);
    }
}

// FMA of one record into the 10 accumulators (2 t-values x 5 r) via v_fma_mix_f32
#define FMAREC(Rk, Xk)                                                              \
    do {                                                                            \
        unsigned x_ = (Xk);                                                         \
        unsigned w01_ = (Rk).y, w23_ = (Rk).z, w4_ = (Rk).w;                        \
        asm("v_fma_mix_f32 %0, %1, %2, %0 op_sel:[0,0,0] op_sel_hi:[1,1,0]"         \
            : "+v"(a0e) : "v"(x_), "v"(w01_));                                      \
        asm("v_fma_mix_f32 %0, %1, %2, %0 op_sel:[1,0,0] op_sel_hi:[1,1,0]"         \
            : "+v"(a0o) : "v"(x_), "v"(w01_));                                      \
        asm("v_fma_mix_f32 %0, %1, %2, %0 op_sel:[0,1,0] op_sel_hi:[1,1,0]"         \
            : "+v"(a1e) : "v"(x_), "v"(w01_));                                      \
        asm("v_fma_mix_f32 %0, %1, %2, %0 op_sel:[1,1,0] op_sel_hi:[1,1,0]"         \
            : "+v"(a1o) : "v"(x_), "v"(w01_));                                      \
        asm("v_fma_mix_f32 %0, %1, %2, %0 op_sel:[0,0,0] op_sel_hi:[1,1,0]"         \
            : "+v"(a2e) : "v"(x_), "v"(w23_));                                      \
        asm("v_fma_mix_f32 %0, %1, %2, %0 op_sel:[1,0,0] op_sel_hi:[1,1,0]"         \
            : "+v"(a2o) : "v"(x_), "v"(w23_));                                      \
        asm("v_fma_mix_f32 %0, %1, %2, %0 op_sel:[0,1,0] op_sel_hi:[1,1,0]"         \
            : "+v"(a3e) : "v"(x_), "v"(w23_));                                      \
        asm("v_fma_mix_f32 %0, %1, %2, %0 op_sel:[1,1,0] op_sel_hi:[1,1,0]"         \
            : "+v"(a3o) : "v"(x_), "v"(w23_));                                      \
        asm("v_fma_mix_f32 %0, %1, %2, %0 op_sel:[0,0,0] op_sel_hi:[1,1,0]"         \
            : "+v"(a4e) : "v"(x_), "v"(w4_));                                       \
        asm("v_fma_mix_f32 %0, %1, %2, %0 op_sel:[1,0,0] op_sel_hi:[1,1,0]"         \
            : "+v"(a4o) : "v"(x_), "v"(w4_));                                       \
    } while (0)

#define LOADSET(P0, P1, P2, P3, XX0, XX1, XX2, XX3, q)                              \
    do {                                                                            \
        P0 = (q)[0]; P1 = (q)[1]; P2 = (q)[2]; P3 = (q)[3];                         \
        XX0 = *(const unsigned*)(xb + (P0.x + lane4));                              \
        XX1 = *(const unsigned*)(xb + (P1.x + lane4));                              \
        XX2 = *(const unsigned*)(xb + (P2.x + lane4));                              \
        XX3 = *(const unsigned*)(xb + (P3.x + lane4));                              \
    } while (0)

// predication-free ping-pong body: ng is wave-uniform (pair-equal padding)
#define ROWBODY(RP)                                                                 \
    do {                                                                            \
        if (ng > 0) {                                                               \
            LOADSET(A0, A1, A2, A3, XA0, XA1, XA2, XA3, (RP));                      \
            int g = 1;                                                              \
            for (; g + 2 <= ng; g += 2) {                                           \
                LOADSET(B0, B1, B2, B3, XB0, XB1, XB2, XB3, (RP) + (g << 2));       \
                FMAREC(A0, XA0); FMAREC(A1, XA1);                                   \
                FMAREC(A2, XA2); FMAREC(A3, XA3);                                   \
                LOADSET(A0, A1, A2, A3, XA0, XA1, XA2, XA3, (RP) + ((g + 1) << 2)); \
                FMAREC(B0, XB0); FMAREC(B1, XB1);                                   \
                FMAREC(B2, XB2); FMAREC(B3, XB3);                                   \
            }                                                                       \
            if (g < ng) {                                                           \
                LOADSET(B0, B1, B2, B3, XB0, XB1, XB2, XB3, (RP) + (g << 2));       \
                FMAREC(A0, XA0); FMAREC(A1, XA1);                                   \
                FMAREC(A2, XA2); FMAREC(A3, XA3);                                   \
                FMAREC(B0, XB0); FMAREC(B1, XB1);                                   \
                FMAREC(B2, XB2); FMAREC(B3, XB3);                                   \
            } else {                                                                \
                FMAREC(A0, XA0); FMAREC(A1, XA1);                                   \
                FMAREC(A2, XA2); FMAREC(A3, XA3);                                   \
            }                                                                       \
        }                                                                           \
    } while (0)

// ---- phase2: 16 rows/block; record range LDS-staged; half-wave per row;
//      half2 gather only VMEM op in loop; ping-pong A/B register sets ----
__global__ __launch_bounds__(256, 4) void k_phase2(
        const __half* __restrict__ xT, const int* __restrict__ rstart,
        const int* __restrict__ plen, const uint4* __restrict__ rec,
        float* __restrict__ out) {
    __shared__ float o_lds[T_DIM * 81];
    __shared__ uint4 recbuf[RECBUF_N];
    const char* xb = (const char*)xT;
    int tid = threadIdx.x;
    int wave = tid >> 6, lane = tid & 63;
    int half = lane >> 5;
    int lane4 = (lane & 31) * 4;
    int p0 = blockIdx.x * 16;
    int start0 = rstart[p0];
    int nblk = rstart[p0 + 15] + plen[p0 + 15] - start0;   // rows contiguous in rec
    bool uselds = (nblk <= RECBUF_N);                      // block-uniform
    if (uselds) {
        for (int i = tid; i < nblk; i += 256) recbuf[i] = rec[start0 + i];
    }
    __syncthreads();
    #pragma unroll
    for (int h = 0; h < 2; ++h) {
        int pa = p0 + wave * 4 + h * 2;
        int myrow = pa + half;
        int ih = rstart[myrow];
        int ng = __builtin_amdgcn_readfirstlane(plen[pa]) >> 2;  // pair-uniform
        float a0e = 0.f, a0o = 0.f, a1e = 0.f, a1o = 0.f, a2e = 0.f;
        float a2o = 0.f, a3e = 0.f, a3o = 0.f, a4e = 0.f, a4o = 0.f;
        uint4 A0, A1, A2, A3, B0, B1, B2, B3;
        unsigned XA0, XA1, XA2, XA3, XB0, XB1, XB2, XB3;
        if (uselds) {
            const uint4* rp = recbuf + (ih - start0);      // ds_read path
            ROWBODY(rp);
        } else {
            const uint4* rp = rec + ih;                    // cold fallback
            ROWBODY(rp);
        }
        int rowl = wave * 4 + h * 2 + half;
        int t0 = (lane & 31) * 2;
        float* d0 = &o_lds[t0 * 81 + rowl * 5];
        d0[0] = a0e; d0[1] = a1e; d0[2] = a2e; d0[3] = a3e; d0[4] = a4e;
        float* d1 = &o_lds[(t0 + 1) * 81 + rowl * 5];
        d1[0] = a0o; d1[1] = a1o; d1[2] = a2o; d1[3] = a3o; d1[4] = a4o;
    }
    __syncthreads();
    int base5 = blockIdx.x * 80;
    for (int i2 = tid; i2 < T_DIM * 80; i2 += 256) {
        int t = i2 / 80;
        int j = i2 - t * 80;
        out[(size_t)t * (N_POST * R_DIM) + base5 + j] = o_lds[t * 81 + j];
    }
}

extern "C" void kernel_launch(void* const* d_in, const int* in_sizes, int n_in,
                              void* d_out, int out_size, void* d_ws, size_t ws_size,
                              hipStream_t stream) {
    const float* inp  = (const float*)d_in[0];
    const int2*  idx2 = (const int2*)d_in[1];
    const float* iw   = (const float*)d_in[2];
    const float* S    = (const float*)d_in[3];
    const int*   sid  = (const int*)d_in[4];
    float* out = (float*)d_out;

    char* ws = (char*)d_ws;
    size_t off = 0;
    auto alloc = [&](size_t bytes) -> void* {
        void* p = ws + off;
        off += (bytes + 255) & ~(size_t)255;
        return p;
    };
    __half* xT            = (__half*)alloc((size_t)N_IN * T_DIM * 2);
    unsigned short* cnt   = (unsigned short*)alloc((size_t)NBUCK * NBLK1 * 2);
    int*   rstart         = (int*)alloc((size_t)N_POST * 4);
    int*   plen           = (int*)alloc((size_t)N_POST * 4);
    uint2* rec1           = (uint2*)alloc((size_t)NBUCK * NBLK1 * CAP * 8);
    uint4* rec            = (uint4*)alloc((size_t)NBUCK * CAPR * 16);

    k_ts<<<CTILES + NBLK1, 1024, 0, stream>>>(inp, xT, idx2, iw, sid, cnt, rec1);
    k_fine<<<NBUCK, 512, 0, stream>>>(rec1, cnt, S, rec, rstart, plen);
    k_phase2<<<N_POST / 16, 256, 0, stream>>>(xT, rstart, plen, rec, out);
}

// Round 18
// 65.035 us; speedup vs baseline: 1.2789x; 1.0424x over previous
//
#include <hip/hip_runtime.h>
#include <hip/hip_fp16.h>

#define N_POST 50000
#define N_IN   17400
#define NNZ_E  1000000
#define T_DIM  64
#define R_DIM  5
#define NT_DIM 10

#define BROWS  256                                  // rows per bucket
#define NBUCK  ((N_POST + BROWS - 1) / BROWS)       // 196
#define EPB    4096                                 // edges per split block
#define NBLK1  ((NNZ_E + EPB - 1) / EPB)            // 245
#define CAP    64                                   // records per (block,bucket) cell
#define FCAP   5632                                 // max records per bucket (mean 5102)
#define CAPR   8192                                 // padded rec stride per bucket (quad pad)
#define CTILES ((N_IN + 63) / 64)                   // 272
#define RECBUF_N 1024                               // staged records per phase2 block

static __device__ __forceinline__ unsigned pack2h(float a, float b) {
    __half2 h = __floats2half2_rn(a, b);
    return *reinterpret_cast<unsigned*>(&h);
}

// ---- fused grid (1024 threads): blocks [0,CTILES) transpose one 64-col tile;
//      blocks [CTILES, CTILES+NBLK1) single-pass bucket binning ----
__global__ __launch_bounds__(1024) void k_ts(const float* __restrict__ x,
                                             __half* __restrict__ xT,
                                             const int2* __restrict__ idx2,
                                             const float* __restrict__ iw,
                                             const int* __restrict__ sid,
                                             unsigned short* __restrict__ cnt,
                                             uint2* __restrict__ rec1) {
    __shared__ float tile[64][65];
    int bb = blockIdx.x;
    int tid = threadIdx.x;
    if (bb < CTILES) {
        int c0 = bb * 64;
        int l = tid & 63, w = tid >> 6;             // w: 0..15
        #pragma unroll
        for (int i = 0; i < 4; ++i) {
            int t = i * 16 + w;
            int c = c0 + l;
            tile[l][t] = (c < N_IN) ? x[t * N_IN + c] : 0.f;
        }
        __syncthreads();
        #pragma unroll
        for (int i = 0; i < 4; ++i) {
            int cc = i * 16 + w;
            int c = c0 + cc;
            if (c < N_IN) xT[c * 64 + l] = __float2half(tile[cc][l]);
        }
        return;
    }
    int* lcur = (int*)&tile[0][0];
    for (int i = tid; i < NBUCK; i += 1024) lcur[i] = 0;
    __syncthreads();
    int blk = bb - CTILES;
    int base = blk * EPB;
    int n = min(EPB, NNZ_E - base);
    for (int i = tid; i < n; i += 1024) {
        int2 rc = idx2[base + i];
        unsigned bk = (unsigned)rc.x >> 8;
        int pos = atomicAdd(&lcur[bk], 1);
        unsigned xx = (unsigned)rc.y | ((unsigned)sid[base + i] << 15)
                    | ((unsigned)(rc.x & 255) << 19);
        rec1[(bk * NBLK1 + blk) * CAP + pos] =
            make_uint2(xx, __float_as_uint(iw[base + i]));
    }
    __syncthreads();
    for (int i = tid; i < NBUCK; i += 1024)
        cnt[i * NBLK1 + blk] = (unsigned short)lcur[i];
}

// ---- per-bucket: parallel slot-compact cells into LDS, row-hist, scan,
//      emit fp16 records padded so QUAD rows (4k..4k+3) have EQUAL length ----
__global__ __launch_bounds__(512) void k_fine(const uint2* __restrict__ rec1,
                                              const unsigned short* __restrict__ cnt,
                                              const float* __restrict__ S,
                                              uint4* __restrict__ rec,
                                              int* __restrict__ rstart,
                                              int* __restrict__ plen) {
    __shared__ uint2 lrec[FCAP];
    __shared__ int scnt[256];
    __shared__ int soff[256];
    __shared__ int lhist[BROWS];
    __shared__ int lsc[BROWS];
    __shared__ int lcur[BROWS];
    __shared__ float s_S[NT_DIM * R_DIM];
    int t = threadIdx.x;
    int b = blockIdx.x;
    int pbase = b * CAPR;
    if (t < NT_DIM * R_DIM) s_S[t] = S[t];
    int cv = 0;
    if (t < 256) {
        cv = (t < NBLK1) ? (int)cnt[b * NBLK1 + t] : 0;
        scnt[t] = cv;
        soff[t] = cv;
        lhist[t] = 0;
    }
    __syncthreads();
    for (int off = 1; off < 256; off <<= 1) {
        int u = 0;
        if (t < 256 && t >= off) u = soff[t - off];
        __syncthreads();
        if (t < 256) soff[t] += u;
        __syncthreads();
    }
    if (t < 256) soff[t] -= cv;                    // exclusive
    __syncthreads();
    const uint2* srcb = rec1 + (size_t)b * NBLK1 * CAP;
    for (int slot = t; slot < NBLK1 * CAP; slot += 512) {
        int cell = slot >> 6;
        int j = slot & 63;
        if (j < scnt[cell]) lrec[soff[cell] + j] = srcb[slot];
    }
    int nrec = soff[255] + scnt[255];
    __syncthreads();
    for (int i = t; i < nrec; i += 512)
        atomicAdd(&lhist[(lrec[i].x >> 19) & 255], 1);
    __syncthreads();
    // quad-equal padded lengths: vp = max over quad of (v rounded to 4)
    if (t < 256) soff[t] = (lhist[t] + 3) & ~3;    // reuse soff as vp4 scratch
    __syncthreads();
    int v = 0, vp = 0;
    if (t < 256) {
        v = lhist[t];
        int b4 = t & ~3;
        vp = max(max(soff[b4], soff[b4 + 1]), max(soff[b4 + 2], soff[b4 + 3]));
        lsc[t] = vp;
    }
    __syncthreads();
    for (int off = 1; off < 256; off <<= 1) {
        int u = 0;
        if (t < 256 && t >= off) u = lsc[t - off];
        __syncthreads();
        if (t < 256) lsc[t] += u;
        __syncthreads();
    }
    if (t < 256) {
        int exclp = lsc[t] - vp;
        int p = b * BROWS + t;
        if (p < N_POST) { rstart[p] = pbase + exclp; plen[p] = vp; }
        lcur[t] = exclp;
    }
    __syncthreads();
    for (int i = t; i < nrec; i += 512) {
        uint2 rc = lrec[i];
        int r = (rc.x >> 19) & 255;
        int pos = atomicAdd(&lcur[r], 1);
        unsigned col = rc.x & 0x7FFF;
        const float* f = &s_S[((rc.x >> 15) & 0xF) * R_DIM];
        float w = __uint_as_float(rc.y);
        uint4 r4;
        r4.x = col << 7;                 // byte offset into fp16 xT
        r4.y = pack2h(w * f[0], w * f[1]);
        r4.z = pack2h(w * f[2], w * f[3]);
        r4.w = pack2h(w * f[4], 0.f);
        rec[pbase + pos] = r4;
    }
    if (t < 256) {
        int exclp = lsc[t] - vp;
        for (int u = v; u < vp; ++u)
            rec[pbase + exclp + u] = make_uint4(0, 0, 0, 0);
    }
}

// FMA of one record into 20 accumulators (4 t-values x 5 r) via v_fma_mix_f32.
// x halves: t0=X.x lo, t1=X.x hi, t2=X.y lo, t3=X.y hi; w halves per r.
#define FMX(acc, xs, xsel, ws, wsel)                                               \
    asm("v_fma_mix_f32 %0, %1, %2, %0 op_sel:[" #xsel "," #wsel ",0] "             \
        "op_sel_hi:[1,1,0]" : "+v"(acc) : "v"(xs), "v"(ws))

#define FMAREC20(Rk, Xk)                                                           \
    do {                                                                           \
        unsigned xlo_ = (Xk).x, xhi_ = (Xk).y;                                     \
        unsigned w01_ = (Rk).y, w23_ = (Rk).z, w4_ = (Rk).w;                       \
        FMX(a00, xlo_, 0, w01_, 0); FMX(a01, xlo_, 0, w01_, 1);                    \
        FMX(a02, xlo_, 0, w23_, 0); FMX(a03, xlo_, 0, w23_, 1);                    \
        FMX(a04, xlo_, 0, w4_,  0);                                               \
        FMX(a10, xhi_, 1, w01_, 0); FMX(a11, xhi_, 1, w01_, 1);                    \
        FMX(a12, xhi_, 1, w23_, 0); FMX(a13, xhi_, 1, w23_, 1);                    \
        FMX(a14, xhi_, 1, w4_,  0);                                               \
    } while (0)
// note: a1x use xhi_ with op_sel 1 -> t1 = X.x hi; a2x/a3x handled below

#define FMAREC20B(Rk, Xk)                                                          \
    do {                                                                           \
        unsigned xlo_ = (Xk).x, xhi_ = (Xk).y;                                     \
        unsigned w01_ = (Rk).y, w23_ = (Rk).z, w4_ = (Rk).w;                       \
        FMX(a00, xlo_, 0, w01_, 0); FMX(a01, xlo_, 0, w01_, 1);                    \
        FMX(a02, xlo_, 0, w23_, 0); FMX(a03, xlo_, 0, w23_, 1);                    \
        FMX(a04, xlo_, 0, w4_,  0);                                               \
        FMX(a10, xlo_, 1, w01_, 0); FMX(a11, xlo_, 1, w01_, 1);                    \
        FMX(a12, xlo_, 1, w23_, 0); FMX(a13, xlo_, 1, w23_, 1);                    \
        FMX(a14, xlo_, 1, w4_,  0);                                               \
        FMX(a20, xhi_, 0, w01_, 0); FMX(a21, xhi_, 0, w01_, 1);                    \
        FMX(a22, xhi_, 0, w23_, 0); FMX(a23, xhi_, 0, w23_, 1);                    \
        FMX(a24, xhi_, 0, w4_,  0);                                               \
        FMX(a30, xhi_, 1, w01_, 0); FMX(a31, xhi_, 1, w01_, 1);                    \
        FMX(a32, xhi_, 1, w23_, 0); FMX(a33, xhi_, 1, w23_, 1);                    \
        FMX(a34, xhi_, 1, w4_,  0);                                               \
    } while (0)

#define LOADSET4(P0, P1, P2, P3, XX0, XX1, XX2, XX3, q_)                           \
    do {                                                                           \
        P0 = (q_)[0]; P1 = (q_)[1]; P2 = (q_)[2]; P3 = (q_)[3];                    \
        XX0 = *(const uint2*)(xb + (P0.x + s8));                                   \
        XX1 = *(const uint2*)(xb + (P1.x + s8));                                   \
        XX2 = *(const uint2*)(xb + (P2.x + s8));                                   \
        XX3 = *(const uint2*)(xb + (P3.x + s8));                                   \
    } while (0)

// ping-pong body; ng is wave-uniform (quad-equal padding)
#define ROWBODY4(RP)                                                               \
    do {                                                                           \
        if (ng > 0) {                                                              \
            LOADSET4(A0, A1, A2, A3, XA0, XA1, XA2, XA3, (RP));                    \
            int g = 1;                                                             \
            for (; g + 2 <= ng; g += 2) {                                          \
                LOADSET4(B0, B1, B2, B3, XB0, XB1, XB2, XB3, (RP) + (g << 2));     \
                FMAREC20B(A0, XA0); FMAREC20B(A1, XA1);                            \
                FMAREC20B(A2, XA2); FMAREC20B(A3, XA3);                            \
                LOADSET4(A0, A1, A2, A3, XA0, XA1, XA2, XA3,                       \
                         (RP) + ((g + 1) << 2));                                   \
                FMAREC20B(B0, XB0); FMAREC20B(B1, XB1);                            \
                FMAREC20B(B2, XB2); FMAREC20B(B3, XB3);                            \
            }                                                                      \
            if (g < ng) {                                                          \
                LOADSET4(B0, B1, B2, B3, XB0, XB1, XB2, XB3, (RP) + (g << 2));     \
                FMAREC20B(A0, XA0); FMAREC20B(A1, XA1);                            \
                FMAREC20B(A2, XA2); FMAREC20B(A3, XA3);                            \
                FMAREC20B(B0, XB0); FMAREC20B(B1, XB1);                            \
                FMAREC20B(B2, XB2); FMAREC20B(B3, XB3);                            \
            } else {                                                               \
                FMAREC20B(A0, XA0); FMAREC20B(A1, XA1);                            \
                FMAREC20B(A2, XA2); FMAREC20B(A3, XA3);                            \
            }                                                                      \
        }                                                                          \
    } while (0)

// ---- phase2: 16 rows/block; quarter-wave (16 lanes) per row; each lane covers
//      4 t-steps via one uint2 gather; record range LDS-staged; ping-pong ----
__global__ __launch_bounds__(256, 4) void k_phase2(
        const __half* __restrict__ xT, const int* __restrict__ rstart,
        const int* __restrict__ plen, const uint4* __restrict__ rec,
        float* __restrict__ out) {
    __shared__ float o_lds[T_DIM * 81];
    __shared__ uint4 recbuf[RECBUF_N];
    const char* xb = (const char*)xT;
    int tid = threadIdx.x;
    int wave = tid >> 6, lane = tid & 63;
    int q = lane >> 4, s = lane & 15;
    int s8 = s * 8;                       // byte offset of my 4 halves in a col row
    int p0 = blockIdx.x * 16;
    int start0 = rstart[p0];
    int nblk = rstart[p0 + 15] + plen[p0 + 15] - start0;   // rows contiguous in rec
    bool uselds = (nblk <= RECBUF_N);                      // block-uniform
    if (uselds) {
        for (int i = tid; i < nblk; i += 256) recbuf[i] = rec[start0 + i];
    }
    __syncthreads();
    int pa = p0 + wave * 4;               // my wave's quad base row
    int myrow = pa + q;
    int ih = rstart[myrow];
    int ng = __builtin_amdgcn_readfirstlane(plen[pa]) >> 2;   // quad-uniform
    float a00 = 0.f, a01 = 0.f, a02 = 0.f, a03 = 0.f, a04 = 0.f;
    float a10 = 0.f, a11 = 0.f, a12 = 0.f, a13 = 0.f, a14 = 0.f;
    float a20 = 0.f, a21 = 0.f, a22 = 0.f, a23 = 0.f, a24 = 0.f;
    float a30 = 0.f, a31 = 0.f, a32 = 0.f, a33 = 0.f, a34 = 0.f;
    uint4 A0, A1, A2, A3, B0, B1, B2, B3;
    uint2 XA0, XA1, XA2, XA3, XB0, XB1, XB2, XB3;
    if (uselds) {
        const uint4* rp = recbuf + (ih - start0);          // ds_read path
        ROWBODY4(rp);
    } else {
        const uint4* rp = rec + ih;                        // cold fallback
        ROWBODY4(rp);
    }
    int rowl = wave * 4 + q;
    {
        float* d0 = &o_lds[(4 * s + 0) * 81 + rowl * 5];
        d0[0] = a00; d0[1] = a01; d0[2] = a02; d0[3] = a03; d0[4] = a04;
        float* d1 = &o_lds[(4 * s + 1) * 81 + rowl * 5];
        d1[0] = a10; d1[1] = a11; d1[2] = a12; d1[3] = a13; d1[4] = a14;
        float* d2 = &o_lds[(4 * s + 2) * 81 + rowl * 5];
        d2[0] = a20; d2[1] = a21; d2[2] = a22; d2[3] = a23; d2[4] = a24;
        float* d3 = &o_lds[(4 * s + 3) * 81 + rowl * 5];
        d3[0] = a30; d3[1] = a31; d3[2] = a32; d3[3] = a33; d3[4] = a34;
    }
    __syncthreads();
    int base5 = blockIdx.x * 80;
    for (int i2 = tid; i2 < T_DIM * 80; i2 += 256) {
        int t = i2 / 80;
        int j = i2 - t * 80;
        out[(size_t)t * (N_POST * R_DIM) + base5 + j] = o_lds[t * 81 + j];
    }
}

extern "C" void kernel_launch(void* const* d_in, const int* in_sizes, int n_in,
                              void* d_out, int out_size, void* d_ws, size_t ws_size,
                              hipStream_t stream) {
    const float* inp  = (const float*)d_in[0];
    const int2*  idx2 = (const int2*)d_in[1];
    const float* iw   = (const float*)d_in[2];
    const float* S    = (const float*)d_in[3];
    const int*   sid  = (const int*)d_in[4];
    float* out = (float*)d_out;

    char* ws = (char*)d_ws;
    size_t off = 0;
    auto alloc = [&](size_t bytes) -> void* {
        void* p = ws + off;
        off += (bytes + 255) & ~(size_t)255;
        return p;
    };
    __half* xT            = (__half*)alloc((size_t)N_IN * T_DIM * 2);
    unsigned short* cnt   = (unsigned short*)alloc((size_t)NBUCK * NBLK1 * 2);
    int*   rstart         = (int*)alloc((size_t)N_POST * 4);
    int*   plen           = (int*)alloc((size_t)N_POST * 4);
    uint2* rec1           = (uint2*)alloc((size_t)NBUCK * NBLK1 * CAP * 8);
    uint4* rec            = (uint4*)alloc((size_t)NBUCK * CAPR * 16);

    k_ts<<<CTILES + NBLK1, 1024, 0, stream>>>(inp, xT, idx2, iw, sid, cnt, rec1);
    k_fine<<<NBUCK, 512, 0, stream>>>(rec1, cnt, S, rec, rstart, plen);
    k_phase2<<<N_POST / 16, 256, 0, stream>>>(xT, rstart, plen, rec, out);
}

// Round 20
// 64.279 us; speedup vs baseline: 1.2940x; 1.0118x over previous
//
#include <hip/hip_runtime.h>
#include <hip/hip_fp16.h>

#define N_POST 50000
#define N_IN   17400
#define NNZ_E  1000000
#define T_DIM  64
#define R_DIM  5
#define NT_DIM 10

#define BROWS  128                                  // rows per bucket
#define NBUCK  ((N_POST + BROWS - 1) / BROWS)       // 391
#define EPB    4096                                 // edges per split block
#define NBLK1  ((NNZ_E + EPB - 1) / EPB)            // 245
#define CAP    48                                   // records per (block,bucket) cell
#define FCAP   3072                                 // max unpadded records per bucket (mean 2560, +10s)
#define CAPR   4608                                 // padded rec stride per bucket (mean ~3390, +16s)
#define CTILES ((N_IN + 63) / 64)                   // 272
#define RECBUF_N 1024                               // staged records per phase2 block

static __device__ __forceinline__ unsigned pack2h(float a, float b) {
    __half2 h = __floats2half2_rn(a, b);
    return *reinterpret_cast<unsigned*>(&h);
}

// ---- fused grid (1024 threads): blocks [0,CTILES) transpose one 64-col tile;
//      blocks [CTILES, CTILES+NBLK1) single-pass bucket binning ----
__global__ __launch_bounds__(1024) void k_ts(const float* __restrict__ x,
                                             __half* __restrict__ xT,
                                             const int2* __restrict__ idx2,
                                             const float* __restrict__ iw,
                                             const int* __restrict__ sid,
                                             unsigned short* __restrict__ cnt,
                                             uint2* __restrict__ rec1) {
    __shared__ float tile[64][65];
    int bb = blockIdx.x;
    int tid = threadIdx.x;
    if (bb < CTILES) {
        int c0 = bb * 64;
        int l = tid & 63, w = tid >> 6;             // w: 0..15
        #pragma unroll
        for (int i = 0; i < 4; ++i) {
            int t = i * 16 + w;
            int c = c0 + l;
            tile[l][t] = (c < N_IN) ? x[t * N_IN + c] : 0.f;
        }
        __syncthreads();
        #pragma unroll
        for (int i = 0; i < 4; ++i) {
            int cc = i * 16 + w;
            int c = c0 + cc;
            if (c < N_IN) xT[c * 64 + l] = __float2half(tile[cc][l]);
        }
        return;
    }
    int* lcur = (int*)&tile[0][0];                  // NBUCK ints fit easily
    for (int i = tid; i < NBUCK; i += 1024) lcur[i] = 0;
    __syncthreads();
    int blk = bb - CTILES;
    int base = blk * EPB;
    int n = min(EPB, NNZ_E - base);
    for (int i = tid; i < n; i += 1024) {
        int2 rc = idx2[base + i];
        unsigned bk = (unsigned)rc.x >> 7;          // row/128
        int pos = atomicAdd(&lcur[bk], 1);
        unsigned xx = (unsigned)rc.y | ((unsigned)sid[base + i] << 15)
                    | ((unsigned)(rc.x & 127) << 19);
        rec1[((size_t)bk * NBLK1 + blk) * CAP + pos] =
            make_uint2(xx, __float_as_uint(iw[base + i]));
    }
    __syncthreads();
    for (int i = tid; i < NBUCK; i += 1024)
        cnt[i * NBLK1 + blk] = (unsigned short)lcur[i];
}

// ---- per-bucket: parallel slot-compact cells into LDS, row-hist, scan,
//      emit fp16 records padded so QUAD rows (4k..4k+3) have EQUAL length ----
__global__ __launch_bounds__(512) void k_fine(const uint2* __restrict__ rec1,
                                              const unsigned short* __restrict__ cnt,
                                              const float* __restrict__ S,
                                              uint4* __restrict__ rec,
                                              int* __restrict__ rstart,
                                              int* __restrict__ plen) {
    __shared__ uint2 lrec[FCAP];
    __shared__ int scnt[256];
    __shared__ int soff[256];
    __shared__ int lhist[BROWS];
    __shared__ int lsc[BROWS];
    __shared__ int lcur[BROWS];
    __shared__ int vp4[BROWS];
    __shared__ float s_S[NT_DIM * R_DIM];
    int t = threadIdx.x;
    int b = blockIdx.x;
    int pbase = b * CAPR;
    if (t < NT_DIM * R_DIM) s_S[t] = S[t];
    int cv = 0;
    if (t < 256) {
        cv = (t < NBLK1) ? (int)cnt[b * NBLK1 + t] : 0;
        scnt[t] = cv;
        soff[t] = cv;
    }
    if (t < BROWS) lhist[t] = 0;
    __syncthreads();
    for (int off = 1; off < 256; off <<= 1) {
        int u = 0;
        if (t < 256 && t >= off) u = soff[t - off];
        __syncthreads();
        if (t < 256) soff[t] += u;
        __syncthreads();
    }
    if (t < 256) soff[t] -= cv;                    // exclusive
    __syncthreads();
    const uint2* srcb = rec1 + (size_t)b * NBLK1 * CAP;
    for (int idx = t; idx < NBLK1 * CAP; idx += 512) {
        int cell = idx / CAP;
        int j = idx - cell * CAP;
        if (j < scnt[cell]) lrec[soff[cell] + j] = srcb[idx];
    }
    int nrec = soff[255] + scnt[255];
    __syncthreads();
    for (int i = t; i < nrec; i += 512)
        atomicAdd(&lhist[(lrec[i].x >> 19) & 127], 1);
    __syncthreads();
    // quad-equal padded lengths: vp = max over quad of (v rounded to 4)
    if (t < BROWS) vp4[t] = (lhist[t] + 3) & ~3;
    __syncthreads();
    int v = 0, vp = 0;
    if (t < BROWS) {
        v = lhist[t];
        int b4 = t & ~3;
        vp = max(max(vp4[b4], vp4[b4 + 1]), max(vp4[b4 + 2], vp4[b4 + 3]));
        lsc[t] = vp;
    }
    __syncthreads();
    for (int off = 1; off < BROWS; off <<= 1) {
        int u = 0;
        if (t < BROWS && t >= off) u = lsc[t - off];
        __syncthreads();
        if (t < BROWS) lsc[t] += u;
        __syncthreads();
    }
    if (t < BROWS) {
        int exclp = lsc[t] - vp;
        int p = b * BROWS + t;
        if (p < N_POST) { rstart[p] = pbase + exclp; plen[p] = vp; }
        lcur[t] = exclp;
    }
    __syncthreads();
    for (int i = t; i < nrec; i += 512) {
        uint2 rc = lrec[i];
        int r = (rc.x >> 19) & 127;
        int pos = atomicAdd(&lcur[r], 1);
        unsigned col = rc.x & 0x7FFF;
        const float* f = &s_S[((rc.x >> 15) & 0xF) * R_DIM];
        float w = __uint_as_float(rc.y);
        uint4 r4;
        r4.x = col << 7;                 // byte offset into fp16 xT
        r4.y = pack2h(w * f[0], w * f[1]);
        r4.z = pack2h(w * f[2], w * f[3]);
        r4.w = pack2h(w * f[4], 0.f);
        rec[pbase + pos] = r4;
    }
    if (t < BROWS) {
        int exclp = lsc[t] - vp;
        for (int u = v; u < vp; ++u)
            rec[pbase + exclp + u] = make_uint4(0, 0, 0, 0);
    }
}

// FMA of one record into 20 accumulators (4 t-values x 5 r) via v_fma_mix_f32.
#define FMX(acc, xs, xsel, ws, wsel)                                               \
    asm("v_fma_mix_f32 %0, %1, %2, %0 op_sel:[" #xsel "," #wsel ",0] "             \
        "op_sel_hi:[1,1,0]" : "+v"(acc) : "v"(xs), "v"(ws))

#define FMAREC20B(Rk, Xk)                                                          \
    do {                                                                           \
        unsigned xlo_ = (Xk).x, xhi_ = (Xk).y;                                     \
        unsigned w01_ = (Rk).y, w23_ = (Rk).z, w4_ = (Rk).w;                       \
        FMX(a00, xlo_, 0, w01_, 0); FMX(a01, xlo_, 0, w01_, 1);                    \
        FMX(a02, xlo_, 0, w23_, 0); FMX(a03, xlo_, 0, w23_, 1);                    \
        FMX(a04, xlo_, 0, w4_,  0);                                               \
        FMX(a10, xlo_, 1, w01_, 0); FMX(a11, xlo_, 1, w01_, 1);                    \
        FMX(a12, xlo_, 1, w23_, 0); FMX(a13, xlo_, 1, w23_, 1);                    \
        FMX(a14, xlo_, 1, w4_,  0);                                               \
        FMX(a20, xhi_, 0, w01_, 0); FMX(a21, xhi_, 0, w01_, 1);                    \
        FMX(a22, xhi_, 0, w23_, 0); FMX(a23, xhi_, 0, w23_, 1);                    \
        FMX(a24, xhi_, 0, w4_,  0);                                               \
        FMX(a30, xhi_, 1, w01_, 0); FMX(a31, xhi_, 1, w01_, 1);                    \
        FMX(a32, xhi_, 1, w23_, 0); FMX(a33, xhi_, 1, w23_, 1);                    \
        FMX(a34, xhi_, 1, w4_,  0);                                               \
    } while (0)

#define LOADSET4(P0, P1, P2, P3, XX0, XX1, XX2, XX3, q_)                           \
    do {                                                                           \
        P0 = (q_)[0]; P1 = (q_)[1]; P2 = (q_)[2]; P3 = (q_)[3];                    \
        XX0 = *(const uint2*)(xb + (P0.x + s8));                                   \
        XX1 = *(const uint2*)(xb + (P1.x + s8));                                   \
        XX2 = *(const uint2*)(xb + (P2.x + s8));                                   \
        XX3 = *(const uint2*)(xb + (P3.x + s8));                                   \
    } while (0)

// ping-pong body; ng is wave-uniform (quad-equal padding)
#define ROWBODY4(RP)                                                               \
    do {                                                                           \
        if (ng > 0) {                                                              \
            LOADSET4(A0, A1, A2, A3, XA0, XA1, XA2, XA3, (RP));                    \
            int g = 1;                                                             \
            for (; g + 2 <= ng; g += 2) {                                          \
                LOADSET4(B0, B1, B2, B3, XB0, XB1, XB2, XB3, (RP) + (g << 2));     \
                FMAREC20B(A0, XA0); FMAREC20B(A1, XA1);                            \
                FMAREC20B(A2, XA2); FMAREC20B(A3, XA3);                            \
                LOADSET4(A0, A1, A2, A3, XA0, XA1, XA2, XA3,                       \
                         (RP) + ((g + 1) << 2));                                   \
                FMAREC20B(B0, XB0); FMAREC20B(B1, XB1);                            \
                FMAREC20B(B2, XB2); FMAREC20B(B3, XB3);                            \
            }                                                                      \
            if (g < ng) {                                                          \
                LOADSET4(B0, B1, B2, B3, XB0, XB1, XB2, XB3, (RP) + (g << 2));     \
                FMAREC20B(A0, XA0); FMAREC20B(A1, XA1);                            \
                FMAREC20B(A2, XA2); FMAREC20B(A3, XA3);                            \
                FMAREC20B(B0, XB0); FMAREC20B(B1, XB1);                            \
                FMAREC20B(B2, XB2); FMAREC20B(B3, XB3);                            \
            } else {                                                               \
                FMAREC20B(A0, XA0); FMAREC20B(A1, XA1);                            \
                FMAREC20B(A2, XA2); FMAREC20B(A3, XA3);                            \
            }                                                                      \
        }                                                                          \
    } while (0)

// ---- phase2: 16 rows/block; quarter-wave (16 lanes) per row; each lane covers
//      4 t-steps via one uint2 gather; record range LDS-staged; ping-pong ----
__global__ __launch_bounds__(256, 4) void k_phase2(
        const __half* __restrict__ xT, const int* __restrict__ rstart,
        const int* __restrict__ plen, const uint4* __restrict__ rec,
        float* __restrict__ out) {
    __shared__ float o_lds[T_DIM * 81];
    __shared__ uint4 recbuf[RECBUF_N];
    const char* xb = (const char*)xT;
    int tid = threadIdx.x;
    int wave = tid >> 6, lane = tid & 63;
    int q = lane >> 4, s = lane & 15;
    int s8 = s * 8;                       // byte offset of my 4 halves in a col row
    int p0 = blockIdx.x * 16;
    int start0 = rstart[p0];
    int nblk = rstart[p0 + 15] + plen[p0 + 15] - start0;   // rows contiguous in rec
    bool uselds = (nblk <= RECBUF_N);                      // block-uniform
    if (uselds) {
        for (int i = tid; i < nblk; i += 256) recbuf[i] = rec[start0 + i];
    }
    __syncthreads();
    int pa = p0 + wave * 4;               // my wave's quad base row
    int myrow = pa + q;
    int ih = rstart[myrow];
    int ng = __builtin_amdgcn_readfirstlane(plen[pa]) >> 2;   // quad-uniform
    float a00 = 0.f, a01 = 0.f, a02 = 0.f, a03 = 0.f, a04 = 0.f;
    float a10 = 0.f, a11 = 0.f, a12 = 0.f, a13 = 0.f, a14 = 0.f;
    float a20 = 0.f, a21 = 0.f, a22 = 0.f, a23 = 0.f, a24 = 0.f;
    float a30 = 0.f, a31 = 0.f, a32 = 0.f, a33 = 0.f, a34 = 0.f;
    uint4 A0, A1, A2, A3, B0, B1, B2, B3;
    uint2 XA0, XA1, XA2, XA3, XB0, XB1, XB2, XB3;
    if (uselds) {
        const uint4* rp = recbuf + (ih - start0);          // ds_read path
        ROWBODY4(rp);
    } else {
        const uint4* rp = rec + ih;                        // cold fallback
        ROWBODY4(rp);
    }
    int rowl = wave * 4 + q;
    {
        float* d0 = &o_lds[(4 * s + 0) * 81 + rowl * 5];
        d0[0] = a00; d0[1] = a01; d0[2] = a02; d0[3] = a03; d0[4] = a04;
        float* d1 = &o_lds[(4 * s + 1) * 81 + rowl * 5];
        d1[0] = a10; d1[1] = a11; d1[2] = a12; d1[3] = a13; d1[4] = a14;
        float* d2 = &o_lds[(4 * s + 2) * 81 + rowl * 5];
        d2[0] = a20; d2[1] = a21; d2[2] = a22; d2[3] = a23; d2[4] = a24;
        float* d3 = &o_lds[(4 * s + 3) * 81 + rowl * 5];
        d3[0] = a30; d3[1] = a31; d3[2] = a32; d3[3] = a33; d3[4] = a34;
    }
    __syncthreads();
    int base5 = blockIdx.x * 80;
    for (int i2 = tid; i2 < T_DIM * 80; i2 += 256) {
        int t = i2 / 80;
        int j = i2 - t * 80;
        out[(size_t)t * (N_POST * R_DIM) + base5 + j] = o_lds[t * 81 + j];
    }
}

extern "C" void kernel_launch(void* const* d_in, const int* in_sizes, int n_in,
                              void* d_out, int out_size, void* d_ws, size_t ws_size,
                              hipStream_t stream) {
    const float* inp  = (const float*)d_in[0];
    const int2*  idx2 = (const int2*)d_in[1];
    const float* iw   = (const float*)d_in[2];
    const float* S    = (const float*)d_in[3];
    const int*   sid  = (const int*)d_in[4];
    float* out = (float*)d_out;

    char* ws = (char*)d_ws;
    size_t off = 0;
    auto alloc = [&](size_t bytes) -> void* {
        void* p = ws + off;
        off += (bytes + 255) & ~(size_t)255;
        return p;
    };
    __half* xT            = (__half*)alloc((size_t)N_IN * T_DIM * 2);
    unsigned short* cnt   = (unsigned short*)alloc((size_t)NBUCK * NBLK1 * 2);
    int*   rstart         = (int*)alloc((size_t)N_POST * 4);
    int*   plen           = (int*)alloc((size_t)N_POST * 4);
    uint2* rec1           = (uint2*)alloc((size_t)NBUCK * NBLK1 * CAP * 8);
    uint4* rec            = (uint4*)alloc((size_t)NBUCK * CAPR * 16);

    k_ts<<<CTILES + NBLK1, 1024, 0, stream>>>(inp, xT, idx2, iw, sid, cnt, rec1);
    k_fine<<<NBUCK, 512, 0, stream>>>(rec1, cnt, S, rec, rstart, plen);
    k_phase2<<<N_POST / 16, 256, 0, stream>>>(xT, rstart, plen, rec, out);
}